// Round 7
// baseline (455.102 us; speedup 1.0000x reference)
//
#include <hip/hip_runtime.h>
#include <hip/hip_fp16.h>

// GCN graph classifier: 3x (GCNConv -> GraphNorm -> [residual] -> ReLU) -> mean-pool -> linear.
// CSR built once (by destination), reused by all 3 convs.
// hs staged in fp16 (64 B rows). GraphNorm fused block-per-graph (sorted batch).
// k_fill: 16 passes (4 src-ranges x 4 dest-ranges), persistent blocks with L1-resident
//   edge chunks -> neighbor lists come out grouped by source range.
// k_gather: 4 source-range passes; per pass only srcs in a 1.6 MB L2-resident slice of hs
//   are gathered (inactive lanes read a cached dummy row) -> random reads become L2 hits.

#define NN 100000
#define NE 1600000
#define NG 1024
#define HD 32
#define EPSV 1e-5f

#define FP_S 4
#define FP_D 4
#define FILL_BLOCKS 2048
#define SRC_RANGE ((NN + FP_S - 1) / FP_S)   // 25000
#define DST_RANGE ((NN + FP_D - 1) / FP_D)   // 25000

#define GP 4
#define GSLICE ((NN + GP - 1) / GP)          // 25000 rows = 1.6 MB fp16 slice

// Graph boundary offsets from sorted batch: gstart[g] = first node of graph g; gstart[NG] = NN.
__global__ __launch_bounds__(256) void k_bound(const int* __restrict__ batch,
                                               int* __restrict__ gstart) {
    int v = blockIdx.x * 256 + threadIdx.x;
    if (v >= NN) return;
    int b = batch[v];
    int bp = (v > 0) ? batch[v - 1] : -1;
    for (int g = bp + 1; g <= b; g++) gstart[g] = v;
    if (v == NN - 1)
        for (int g = b + 1; g <= NG; g++) gstart[g] = NN;
}

__global__ __launch_bounds__(256) void k_count(const int* __restrict__ col,
                                               int* __restrict__ deg) {
    int e = blockIdx.x * 256 + threadIdx.x;
    if (e < NE) atomicAdd(&deg[col[e]], 1);
}

// deg[] holds edge-count only (zeroed); total slots per node = deg+1 (self loop).
// Wave-level exclusive scan -> start offsets; one global atomic per wave.
__global__ __launch_bounds__(256) void k_alloc(const int* __restrict__ deg,
                                               int* __restrict__ start,
                                               float* __restrict__ dinv,
                                               int* __restrict__ counter) {
    int v = blockIdx.x * 256 + threadIdx.x;
    int lane = threadIdx.x & 63;
    int d = (v < NN) ? (deg[v] + 1) : 0;
    int incl = d;
    #pragma unroll
    for (int off = 1; off < 64; off <<= 1) {
        int n = __shfl_up(incl, off);
        if (lane >= off) incl += n;
    }
    int total = __shfl(incl, 63);
    int base = 0;
    if (lane == 63) base = atomicAdd(counter, total);
    base = __shfl(base, 63);
    if (v < NN) {
        start[v] = base + incl - d;
        dinv[v] = rsqrtf((float)d);
    }
}

// 16-pass CSR fill: src-range outer (=> lists grouped by source), dest-range inner
// (=> fill[] atomic region 100 KB L2-resident per pass). Persistent blocks own a fixed
// ~6.6 KB edge chunk, L1-resident across all 16 scans.
__global__ __launch_bounds__(256) void k_fill(const int* __restrict__ row,
                                              const int* __restrict__ col,
                                              const int* __restrict__ start,
                                              int* __restrict__ fill,
                                              int* __restrict__ csr_src) {
    const int total = NE + NN;
    const int chunk = (total + FILL_BLOCKS - 1) / FILL_BLOCKS;
    int c0 = blockIdx.x * chunk;
    int c1 = min(c0 + chunk, total);
    for (int sp = 0; sp < FP_S; sp++) {
        int slo = sp * SRC_RANGE, shi = slo + SRC_RANGE;
        for (int dp = 0; dp < FP_D; dp++) {
            int dlo = dp * DST_RANGE, dhi = dlo + DST_RANGE;
            for (int e = c0 + threadIdx.x; e < c1; e += 256) {
                int r, c;
                if (e < NE) { r = row[e]; c = col[e]; }
                else        { r = e - NE; c = r; }       // self loops
                if (r >= slo && r < shi && c >= dlo && c < dhi) {
                    int pos = start[c] + atomicAdd(&fill[c], 1);
                    csr_src[pos] = r;
                }
            }
        }
    }
}

// hs[v][f] = (fp16) dinv[v] * sum_k xin[v][k] * W[k][f]; thread per (node, feature-octet).
template <int K>
__global__ __launch_bounds__(256) void k_premul(const float* __restrict__ xin,
                                                const float* __restrict__ W,
                                                const float* __restrict__ dinv,
                                                __half* __restrict__ hs) {
    __shared__ float sW[K * HD];
    for (int i = threadIdx.x; i < K * HD; i += 256) sW[i] = W[i];
    __syncthreads();
    int t = blockIdx.x * 256 + threadIdx.x;
    int v = t >> 2, o = t & 3;
    if (v >= NN) return;
    const float* xv = xin + (size_t)v * K;
    float acc[8] = {0.f, 0.f, 0.f, 0.f, 0.f, 0.f, 0.f, 0.f};
    #pragma unroll
    for (int k = 0; k < K; k++) {
        float xk = xv[k];
        #pragma unroll
        for (int j = 0; j < 8; j++) acc[j] += xk * sW[k * HD + o * 8 + j];
    }
    float dv = dinv[v];
    __half2 h[4];
    #pragma unroll
    for (int j = 0; j < 4; j++)
        h[j] = __floats2half2_rn(dv * acc[2 * j], dv * acc[2 * j + 1]);
    *reinterpret_cast<float4*>(hs + (size_t)v * HD + o * 8) = *reinterpret_cast<float4*>(h);
}

// One wave per destination node: 16 edge-slots x 4 feature-quads (16 B fp16 per lane).
// 4 source-range passes: per pass only entries whose src is in the current L2-resident
// 1.6 MB slice of hs are accumulated; inactive lanes read a cached dummy row of the slice.
// fp32 accumulate throughout.
__global__ __launch_bounds__(256) void k_gather(const __half* __restrict__ hs,
                                                const int* __restrict__ csr_src,
                                                const int* __restrict__ start,
                                                const int* __restrict__ deg,
                                                const float* __restrict__ dinv,
                                                const float* __restrict__ bias,
                                                float* __restrict__ outb) {
    int wid = (blockIdx.x * 256 + threadIdx.x) >> 6;
    if (wid >= NN) return;
    int lane = threadIdx.x & 63;
    int q = lane & 3;      // feature quad: halves q*8 .. q*8+7
    int es = lane >> 2;    // edge slot 0..15
    int s = start[wid], d = deg[wid] + 1;
    bool a0 = (es < d);
    bool a1 = (es + 16 < d);
    int src0 = a0 ? csr_src[s + es] : 0;
    int src1 = a1 ? csr_src[s + es + 16] : 0;
    float acc[8] = {0.f, 0.f, 0.f, 0.f, 0.f, 0.f, 0.f, 0.f};

    #pragma unroll
    for (int p = 0; p < GP; p++) {
        int slo = p * GSLICE, shi = slo + GSLICE;
        bool r0 = a0 && (src0 >= slo) && (src0 < shi);
        bool r1 = a1 && (src1 >= slo) && (src1 < shi);
        int t0 = r0 ? src0 : slo;     // dummy: first row of current slice (cached)
        int t1 = r1 ? src1 : slo;
        float4 raw0 = *reinterpret_cast<const float4*>(hs + (size_t)t0 * HD + q * 8);
        float4 raw1 = *reinterpret_cast<const float4*>(hs + (size_t)t1 * HD + q * 8);
        float m0 = r0 ? 1.f : 0.f;
        float m1 = r1 ? 1.f : 0.f;
        {
            const __half2* hp = reinterpret_cast<const __half2*>(&raw0);
            #pragma unroll
            for (int j = 0; j < 4; j++) {
                float2 f2 = __half22float2(hp[j]);
                acc[2 * j]     += m0 * f2.x;
                acc[2 * j + 1] += m0 * f2.y;
            }
        }
        {
            const __half2* hp = reinterpret_cast<const __half2*>(&raw1);
            #pragma unroll
            for (int j = 0; j < 4; j++) {
                float2 f2 = __half22float2(hp[j]);
                acc[2 * j]     += m1 * f2.x;
                acc[2 * j + 1] += m1 * f2.y;
            }
        }
    }
    // rare tail (deg+1 > 32): Poisson(16) tail, ~0.02% of nodes; unsliced.
    for (int i = es + 32; i < d; i += 16) {
        int src = csr_src[s + i];
        float4 raw = *reinterpret_cast<const float4*>(hs + (size_t)src * HD + q * 8);
        const __half2* hp = reinterpret_cast<const __half2*>(&raw);
        #pragma unroll
        for (int j = 0; j < 4; j++) {
            float2 f2 = __half22float2(hp[j]);
            acc[2 * j]     += f2.x;
            acc[2 * j + 1] += f2.y;
        }
    }
    #pragma unroll
    for (int off = 4; off < 64; off <<= 1) {
        #pragma unroll
        for (int j = 0; j < 8; j++) acc[j] += __shfl_xor(acc[j], off);
    }
    if (es == 0) {
        float dv = dinv[wid];
        float4 w0, w1;
        w0.x = bias[q * 8 + 0] + dv * acc[0];
        w0.y = bias[q * 8 + 1] + dv * acc[1];
        w0.z = bias[q * 8 + 2] + dv * acc[2];
        w0.w = bias[q * 8 + 3] + dv * acc[3];
        w1.x = bias[q * 8 + 4] + dv * acc[4];
        w1.y = bias[q * 8 + 5] + dv * acc[5];
        w1.z = bias[q * 8 + 6] + dv * acc[6];
        w1.w = bias[q * 8 + 7] + dv * acc[7];
        float* op = outb + (size_t)wid * HD + q * 8;
        *reinterpret_cast<float4*>(op)     = w0;
        *reinterpret_cast<float4*>(op + 4) = w1;
    }
}

// Fused GraphNorm (stats + normalize) + optional residual + ReLU + optional mean-pool+linear.
// One block per graph (batch sorted => contiguous node range). y = A*x + B.
template <bool RES, bool POOL>
__global__ __launch_bounds__(256) void k_gnorm(const float* __restrict__ o,
                                               const int* __restrict__ gstart,
                                               const float* __restrict__ gamma,
                                               const float* __restrict__ beta,
                                               const float* __restrict__ msc,
                                               const float* __restrict__ xprev,
                                               float* __restrict__ xout,
                                               const float* __restrict__ Wl,
                                               const float* __restrict__ bl,
                                               float* __restrict__ outf) {
    int g = blockIdx.x;
    int s = gstart[g], e = gstart[g + 1];
    int f = threadIdx.x & 31, nl = threadIdx.x >> 5;   // 8 node-lanes x 32 features
    float as = 0.f, aq = 0.f;
    for (int v = s + nl; v < e; v += 8) {
        float xv = o[(size_t)v * HD + f];
        as += xv;
        aq += xv * xv;
    }
    __shared__ float ls[256], lq[256];
    __shared__ float sA[HD], sB[HD];
    ls[threadIdx.x] = as;
    lq[threadIdx.x] = aq;
    __syncthreads();
    if (threadIdx.x < HD) {
        float ss = 0.f, qq = 0.f;
        #pragma unroll
        for (int k = 0; k < 8; k++) { ss += ls[k * 32 + f]; qq += lq[k * 32 + f]; }
        float inv = 1.f / fmaxf((float)(e - s), 1.f);
        float m = ss * inv, mq = qq * inv, ms = msc[f];
        // var = E[(x - m*ms)^2] = E[x^2] - m^2 * ms * (2 - ms)
        float var = mq - m * m * ms * (2.f - ms);
        float A = gamma[f] * rsqrtf(var + EPSV);
        sA[f] = A;
        sB[f] = beta[f] - A * m * ms;
    }
    __syncthreads();
    float A = sA[f], B = sB[f];
    float pool = 0.f;
    for (int v = s + nl; v < e; v += 8) {
        float xv = o[(size_t)v * HD + f];
        float y = A * xv + B;
        if (RES) y += xprev[(size_t)v * HD + f];
        y = fmaxf(y, 0.f);
        xout[(size_t)v * HD + f] = y;
        if (POOL) pool += y;
    }
    if (POOL) {
        __syncthreads();
        ls[threadIdx.x] = pool;
        __syncthreads();
        if (threadIdx.x < HD) {
            float ss = 0.f;
            #pragma unroll
            for (int k = 0; k < 8; k++) ss += ls[k * 32 + f];
            lq[f] = ss / fmaxf((float)(e - s), 1.f);   // reuse lq: per-feature graph mean
        }
        __syncthreads();
        if (threadIdx.x < 3) {
            float acc = bl[threadIdx.x];
            #pragma unroll
            for (int f2 = 0; f2 < HD; f2++) acc += lq[f2] * Wl[f2 * 3 + threadIdx.x];
            outf[g * 3 + threadIdx.x] = acc;
        }
    }
}

extern "C" void kernel_launch(void* const* d_in, const int* in_sizes, int n_in,
                              void* d_out, int out_size, void* d_ws, size_t ws_size,
                              hipStream_t stream) {
    const float* x     = (const float*)d_in[0];
    const int*   ei    = (const int*)d_in[1];     // [2, NE]
    const int*   batch = (const int*)d_in[2];
    const float* W1 = (const float*)d_in[3];
    const float* b1 = (const float*)d_in[4];
    const float* W2 = (const float*)d_in[5];
    const float* b2 = (const float*)d_in[6];
    const float* W3 = (const float*)d_in[7];
    const float* b3 = (const float*)d_in[8];
    const float* g1 = (const float*)d_in[9];
    const float* be1 = (const float*)d_in[10];
    const float* ms1 = (const float*)d_in[11];
    const float* g2 = (const float*)d_in[12];
    const float* be2 = (const float*)d_in[13];
    const float* ms2 = (const float*)d_in[14];
    const float* g3 = (const float*)d_in[15];
    const float* be3 = (const float*)d_in[16];
    const float* ms3 = (const float*)d_in[17];
    const float* Wl = (const float*)d_in[18];
    const float* bl = (const float*)d_in[19];
    float* out = (float*)d_out;

    const int* row = ei;
    const int* col = ei + NE;

    // ---- workspace layout (16B aligned) ----
    char* ws = (char*)d_ws;
    size_t off = 0;
    // zeroed region:
    int*   fill    = (int*)(ws + off);   off += (size_t)NN * 4;
    int*   deg     = (int*)(ws + off);   off += (size_t)NN * 4;
    int*   counter = (int*)(ws + off);   off += 16;
    size_t zero_bytes = off;
    // non-zeroed region:
    int*   start   = (int*)(ws + off);   off += (size_t)NN * 4;
    float* dinv    = (float*)(ws + off); off += (size_t)NN * 4;
    int*   gstart  = (int*)(ws + off);   off += (size_t)(NG + 4) * 4;
    int*   csr_src = (int*)(ws + off);   off += (size_t)(NE + NN) * 4;
    __half* bufH   = (__half*)(ws + off); off += (size_t)NN * HD * 2;
    float* bufO    = (float*)(ws + off); off += (size_t)NN * HD * 4;
    float* bufX    = (float*)(ws + off); off += (size_t)NN * HD * 4;
    (void)ws_size; (void)in_sizes; (void)n_in; (void)out_size;

    hipMemsetAsync(ws, 0, zero_bytes, stream);

    const int nb_n   = (NN + 255) / 256;             // 391
    const int nb_e   = (NE + 255) / 256;             // 6250
    const int nb_no  = (NN * 4 + 255) / 256;         // 1563  (node-octet threads)
    const int nb_gw  = (NN * 64 + 255) / 256;        // 25000 (wave per node)

    // ---- CSR build (once, reused by all 3 convs) ----
    k_bound<<<nb_n, 256, 0, stream>>>(batch, gstart);
    k_count<<<nb_e, 256, 0, stream>>>(col, deg);
    k_alloc<<<nb_n, 256, 0, stream>>>(deg, start, dinv, counter);
    k_fill <<<FILL_BLOCKS, 256, 0, stream>>>(row, col, start, fill, csr_src);

    // ---- layer 1 ----
    k_premul<3><<<nb_no, 256, 0, stream>>>(x, W1, dinv, bufH);
    k_gather<<<nb_gw, 256, 0, stream>>>(bufH, csr_src, start, deg, dinv, b1, bufO);
    k_gnorm<false, false><<<NG, 256, 0, stream>>>(bufO, gstart, g1, be1, ms1,
                                                  nullptr, bufX, nullptr, nullptr, nullptr);

    // ---- layer 2 ----
    k_premul<HD><<<nb_no, 256, 0, stream>>>(bufX, W2, dinv, bufH);
    k_gather<<<nb_gw, 256, 0, stream>>>(bufH, csr_src, start, deg, dinv, b2, bufO);
    k_gnorm<true, false><<<NG, 256, 0, stream>>>(bufO, gstart, g2, be2, ms2,
                                                 bufX, bufX, nullptr, nullptr, nullptr);

    // ---- layer 3 (pool + linear fused) ----
    k_premul<HD><<<nb_no, 256, 0, stream>>>(bufX, W3, dinv, bufH);
    k_gather<<<nb_gw, 256, 0, stream>>>(bufH, csr_src, start, deg, dinv, b3, bufO);
    k_gnorm<true, true><<<NG, 256, 0, stream>>>(bufO, gstart, g3, be3, ms3,
                                                bufX, bufX, Wl, bl, out);
}

// Round 9
// 427.493 us; speedup vs baseline: 1.0646x; 1.0646x over previous
//
#include <hip/hip_runtime.h>
#include <hip/hip_fp16.h>

// GCN graph classifier: 3x (GCNConv -> GraphNorm -> [residual] -> ReLU) -> mean-pool -> linear.
// CSR built once (by destination), reused by all 3 convs.
// hs staged in fp16 (64 B rows). GraphNorm fused block-per-graph (sorted batch).
// k_count / k_fill: XCD-partitioned (blockIdx&7 ~ XCD, round-robin dispatch) -- each XCD
//   group owns 1/8 of destinations, so its atomic region (50 KB) and scatter-write region
//   (~850 KB) stay resident in ITS OWN L2 => writes combine, write-back ~= payload.
//   (Perf heuristic only: if block->XCD mapping differs, it just runs at round-6 speed.)
// k_gather: 16 edge-slots x 4 feature-quads (16 B fp16/lane), 2-deep pipelined (round-6 form).

#define NN 100000
#define NE 1600000
#define NG 1024
#define HD 32
#define EPSV 1e-5f

#define NXCD 8
#define DR8 ((NN + NXCD - 1) / NXCD)        // 12500 dests per XCD group
#define FILL_BLOCKS 2048
#define COUNT_BLOCKS 2048

// Graph boundary offsets from sorted batch: gstart[g] = first node of graph g; gstart[NG] = NN.
__global__ __launch_bounds__(256) void k_bound(const int* __restrict__ batch,
                                               int* __restrict__ gstart) {
    int v = blockIdx.x * 256 + threadIdx.x;
    if (v >= NN) return;
    int b = batch[v];
    int bp = (v > 0) ? batch[v - 1] : -1;
    for (int g = bp + 1; g <= b; g++) gstart[g] = v;
    if (v == NN - 1)
        for (int g = b + 1; g <= NG; g++) gstart[g] = NN;
}

// XCD-partitioned degree count: group (bid&7) counts only dests in its 50 KB deg slice.
__global__ __launch_bounds__(256) void k_count(const int* __restrict__ col,
                                               int* __restrict__ deg) {
    int grp = blockIdx.x & (NXCD - 1);
    int bin = blockIdx.x / NXCD;
    const int NB = COUNT_BLOCKS / NXCD;
    int lo = grp * DR8, hi = min(lo + DR8, NN);
    const int chunk = (NE + NB - 1) / NB;
    int c0 = bin * chunk, c1 = min(c0 + chunk, NE);
    for (int e = c0 + threadIdx.x; e < c1; e += 256) {
        int c = col[e];
        if (c >= lo && c < hi) atomicAdd(&deg[c], 1);
    }
}

// deg[] holds edge-count only (zeroed); total slots per node = deg+1 (self loop).
// Wave-level exclusive scan -> start offsets; one global atomic per wave.
__global__ __launch_bounds__(256) void k_alloc(const int* __restrict__ deg,
                                               int* __restrict__ start,
                                               float* __restrict__ dinv,
                                               int* __restrict__ counter) {
    int v = blockIdx.x * 256 + threadIdx.x;
    int lane = threadIdx.x & 63;
    int d = (v < NN) ? (deg[v] + 1) : 0;
    int incl = d;
    #pragma unroll
    for (int off = 1; off < 64; off <<= 1) {
        int n = __shfl_up(incl, off);
        if (lane >= off) incl += n;
    }
    int total = __shfl(incl, 63);
    int base = 0;
    if (lane == 63) base = atomicAdd(counter, total);
    base = __shfl(base, 63);
    if (v < NN) {
        start[v] = base + incl - d;
        dinv[v] = rsqrtf((float)d);
    }
}

// XCD-partitioned CSR fill: group (bid&7) scatters only dests in its range, so its
// csr_src write region (~850 KB) + fill[] atomic region (50 KB) are L2-resident in its
// own XCD => every 64 B line absorbs all its ~17 writes before one write-back.
__global__ __launch_bounds__(256) void k_fill(const int* __restrict__ row,
                                              const int* __restrict__ col,
                                              const int* __restrict__ start,
                                              int* __restrict__ fill,
                                              int* __restrict__ csr_src) {
    int grp = blockIdx.x & (NXCD - 1);
    int bin = blockIdx.x / NXCD;
    const int NB = FILL_BLOCKS / NXCD;
    int lo = grp * DR8, hi = min(lo + DR8, NN);
    const int total = NE + NN;
    const int chunk = (total + NB - 1) / NB;
    int c0 = bin * chunk, c1 = min(c0 + chunk, total);
    for (int e = c0 + threadIdx.x; e < c1; e += 256) {
        int r, c;
        if (e < NE) { r = row[e]; c = col[e]; }
        else        { r = e - NE; c = r; }       // self loops
        if (c >= lo && c < hi) {
            int pos = start[c] + atomicAdd(&fill[c], 1);
            csr_src[pos] = r;
        }
    }
}

// hs[v][f] = (fp16) dinv[v] * sum_k xin[v][k] * W[k][f]; thread per (node, feature-octet).
template <int K>
__global__ __launch_bounds__(256) void k_premul(const float* __restrict__ xin,
                                                const float* __restrict__ W,
                                                const float* __restrict__ dinv,
                                                __half* __restrict__ hs) {
    __shared__ float sW[K * HD];
    for (int i = threadIdx.x; i < K * HD; i += 256) sW[i] = W[i];
    __syncthreads();
    int t = blockIdx.x * 256 + threadIdx.x;
    int v = t >> 2, o = t & 3;
    if (v >= NN) return;
    const float* xv = xin + (size_t)v * K;
    float acc[8] = {0.f, 0.f, 0.f, 0.f, 0.f, 0.f, 0.f, 0.f};
    #pragma unroll
    for (int k = 0; k < K; k++) {
        float xk = xv[k];
        #pragma unroll
        for (int j = 0; j < 8; j++) acc[j] += xk * sW[k * HD + o * 8 + j];
    }
    float dv = dinv[v];
    __half2 h[4];
    #pragma unroll
    for (int j = 0; j < 4; j++)
        h[j] = __floats2half2_rn(dv * acc[2 * j], dv * acc[2 * j + 1]);
    *reinterpret_cast<float4*>(hs + (size_t)v * HD + o * 8) = *reinterpret_cast<float4*>(h);
}

// One wave per destination node: 16 edge-slots x 4 feature-quads (16 B fp16 per lane).
// 2-deep software pipeline (avg deg+1 ~ 17 -> exactly 2 iterations for most waves).
__global__ __launch_bounds__(256) void k_gather(const __half* __restrict__ hs,
                                                const int* __restrict__ csr_src,
                                                const int* __restrict__ start,
                                                const int* __restrict__ deg,
                                                const float* __restrict__ dinv,
                                                const float* __restrict__ bias,
                                                float* __restrict__ outb) {
    int wid = (blockIdx.x * 256 + threadIdx.x) >> 6;
    if (wid >= NN) return;
    int lane = threadIdx.x & 63;
    int q = lane & 3;      // feature quad: halves q*8 .. q*8+7
    int es = lane >> 2;    // edge slot 0..15
    int s = start[wid], d = deg[wid] + 1;
    float acc[8] = {0.f, 0.f, 0.f, 0.f, 0.f, 0.f, 0.f, 0.f};

    bool a0 = (es < d);
    bool a1 = (es + 16 < d);
    int src0 = a0 ? csr_src[s + es] : 0;
    int src1 = a1 ? csr_src[s + es + 16] : 0;
    float4 raw0 = *reinterpret_cast<const float4*>(hs + (size_t)src0 * HD + q * 8);
    float4 raw1 = *reinterpret_cast<const float4*>(hs + (size_t)src1 * HD + q * 8);
    float m0 = a0 ? 1.f : 0.f;
    float m1 = a1 ? 1.f : 0.f;
    {
        const __half2* hp = reinterpret_cast<const __half2*>(&raw0);
        #pragma unroll
        for (int j = 0; j < 4; j++) {
            float2 f2 = __half22float2(hp[j]);
            acc[2 * j]     += m0 * f2.x;
            acc[2 * j + 1] += m0 * f2.y;
        }
    }
    {
        const __half2* hp = reinterpret_cast<const __half2*>(&raw1);
        #pragma unroll
        for (int j = 0; j < 4; j++) {
            float2 f2 = __half22float2(hp[j]);
            acc[2 * j]     += m1 * f2.x;
            acc[2 * j + 1] += m1 * f2.y;
        }
    }
    // rare tail (deg+1 > 32): Poisson(16) tail, ~0.02% of nodes
    for (int i = es + 32; i < d; i += 16) {
        int src = csr_src[s + i];
        float4 raw = *reinterpret_cast<const float4*>(hs + (size_t)src * HD + q * 8);
        const __half2* hp = reinterpret_cast<const __half2*>(&raw);
        #pragma unroll
        for (int j = 0; j < 4; j++) {
            float2 f2 = __half22float2(hp[j]);
            acc[2 * j]     += f2.x;
            acc[2 * j + 1] += f2.y;
        }
    }
    #pragma unroll
    for (int off = 4; off < 64; off <<= 1) {
        #pragma unroll
        for (int j = 0; j < 8; j++) acc[j] += __shfl_xor(acc[j], off);
    }
    if (es == 0) {
        float dv = dinv[wid];
        float4 w0, w1;
        w0.x = bias[q * 8 + 0] + dv * acc[0];
        w0.y = bias[q * 8 + 1] + dv * acc[1];
        w0.z = bias[q * 8 + 2] + dv * acc[2];
        w0.w = bias[q * 8 + 3] + dv * acc[3];
        w1.x = bias[q * 8 + 4] + dv * acc[4];
        w1.y = bias[q * 8 + 5] + dv * acc[5];
        w1.z = bias[q * 8 + 6] + dv * acc[6];
        w1.w = bias[q * 8 + 7] + dv * acc[7];
        float* op = outb + (size_t)wid * HD + q * 8;
        *reinterpret_cast<float4*>(op)     = w0;
        *reinterpret_cast<float4*>(op + 4) = w1;
    }
}

// Fused GraphNorm (stats + normalize) + optional residual + ReLU + optional mean-pool+linear.
// One block per graph (batch sorted => contiguous node range). y = A*x + B.
template <bool RES, bool POOL>
__global__ __launch_bounds__(256) void k_gnorm(const float* __restrict__ o,
                                               const int* __restrict__ gstart,
                                               const float* __restrict__ gamma,
                                               const float* __restrict__ beta,
                                               const float* __restrict__ msc,
                                               const float* __restrict__ xprev,
                                               float* __restrict__ xout,
                                               const float* __restrict__ Wl,
                                               const float* __restrict__ bl,
                                               float* __restrict__ outf) {
    int g = blockIdx.x;
    int s = gstart[g], e = gstart[g + 1];
    int f = threadIdx.x & 31, nl = threadIdx.x >> 5;   // 8 node-lanes x 32 features
    float as = 0.f, aq = 0.f;
    for (int v = s + nl; v < e; v += 8) {
        float xv = o[(size_t)v * HD + f];
        as += xv;
        aq += xv * xv;
    }
    __shared__ float ls[256], lq[256];
    __shared__ float sA[HD], sB[HD];
    ls[threadIdx.x] = as;
    lq[threadIdx.x] = aq;
    __syncthreads();
    if (threadIdx.x < HD) {
        float ss = 0.f, qq = 0.f;
        #pragma unroll
        for (int k = 0; k < 8; k++) { ss += ls[k * 32 + f]; qq += lq[k * 32 + f]; }
        float inv = 1.f / fmaxf((float)(e - s), 1.f);
        float m = ss * inv, mq = qq * inv, ms = msc[f];
        // var = E[(x - m*ms)^2] = E[x^2] - m^2 * ms * (2 - ms)
        float var = mq - m * m * ms * (2.f - ms);
        float A = gamma[f] * rsqrtf(var + EPSV);
        sA[f] = A;
        sB[f] = beta[f] - A * m * ms;
    }
    __syncthreads();
    float A = sA[f], B = sB[f];
    float pool = 0.f;
    for (int v = s + nl; v < e; v += 8) {
        float xv = o[(size_t)v * HD + f];
        float y = A * xv + B;
        if (RES) y += xprev[(size_t)v * HD + f];
        y = fmaxf(y, 0.f);
        xout[(size_t)v * HD + f] = y;
        if (POOL) pool += y;
    }
    if (POOL) {
        __syncthreads();
        ls[threadIdx.x] = pool;
        __syncthreads();
        if (threadIdx.x < HD) {
            float ss = 0.f;
            #pragma unroll
            for (int k = 0; k < 8; k++) ss += ls[k * 32 + f];
            lq[f] = ss / fmaxf((float)(e - s), 1.f);   // reuse lq: per-feature graph mean
        }
        __syncthreads();
        if (threadIdx.x < 3) {
            float acc = bl[threadIdx.x];
            #pragma unroll
            for (int f2 = 0; f2 < HD; f2++) acc += lq[f2] * Wl[f2 * 3 + threadIdx.x];
            outf[g * 3 + threadIdx.x] = acc;
        }
    }
}

extern "C" void kernel_launch(void* const* d_in, const int* in_sizes, int n_in,
                              void* d_out, int out_size, void* d_ws, size_t ws_size,
                              hipStream_t stream) {
    const float* x     = (const float*)d_in[0];
    const int*   ei    = (const int*)d_in[1];     // [2, NE]
    const int*   batch = (const int*)d_in[2];
    const float* W1 = (const float*)d_in[3];
    const float* b1 = (const float*)d_in[4];
    const float* W2 = (const float*)d_in[5];
    const float* b2 = (const float*)d_in[6];
    const float* W3 = (const float*)d_in[7];
    const float* b3 = (const float*)d_in[8];
    const float* g1 = (const float*)d_in[9];
    const float* be1 = (const float*)d_in[10];
    const float* ms1 = (const float*)d_in[11];
    const float* g2 = (const float*)d_in[12];
    const float* be2 = (const float*)d_in[13];
    const float* ms2 = (const float*)d_in[14];
    const float* g3 = (const float*)d_in[15];
    const float* be3 = (const float*)d_in[16];
    const float* ms3 = (const float*)d_in[17];
    const float* Wl = (const float*)d_in[18];
    const float* bl = (const float*)d_in[19];
    float* out = (float*)d_out;

    const int* row = ei;
    const int* col = ei + NE;

    // ---- workspace layout (16B aligned) ----
    char* ws = (char*)d_ws;
    size_t off = 0;
    // zeroed region:
    int*   fill    = (int*)(ws + off);   off += (size_t)NN * 4;
    int*   deg     = (int*)(ws + off);   off += (size_t)NN * 4;
    int*   counter = (int*)(ws + off);   off += 16;
    size_t zero_bytes = off;
    // non-zeroed region:
    int*   start   = (int*)(ws + off);   off += (size_t)NN * 4;
    float* dinv    = (float*)(ws + off); off += (size_t)NN * 4;
    int*   gstart  = (int*)(ws + off);   off += (size_t)(NG + 4) * 4;
    int*   csr_src = (int*)(ws + off);   off += (size_t)(NE + NN) * 4;
    __half* bufH   = (__half*)(ws + off); off += (size_t)NN * HD * 2;
    float* bufO    = (float*)(ws + off); off += (size_t)NN * HD * 4;
    float* bufX    = (float*)(ws + off); off += (size_t)NN * HD * 4;
    (void)ws_size; (void)in_sizes; (void)n_in; (void)out_size;

    hipMemsetAsync(ws, 0, zero_bytes, stream);

    const int nb_n   = (NN + 255) / 256;             // 391
    const int nb_no  = (NN * 4 + 255) / 256;         // 1563  (node-octet threads)
    const int nb_gw  = (NN * 64 + 255) / 256;        // 25000 (wave per node)

    // ---- CSR build (once, reused by all 3 convs) ----
    k_bound<<<nb_n, 256, 0, stream>>>(batch, gstart);
    k_count<<<COUNT_BLOCKS, 256, 0, stream>>>(col, deg);
    k_alloc<<<nb_n, 256, 0, stream>>>(deg, start, dinv, counter);
    k_fill <<<FILL_BLOCKS, 256, 0, stream>>>(row, col, start, fill, csr_src);

    // ---- layer 1 ----
    k_premul<3><<<nb_no, 256, 0, stream>>>(x, W1, dinv, bufH);
    k_gather<<<nb_gw, 256, 0, stream>>>(bufH, csr_src, start, deg, dinv, b1, bufO);
    k_gnorm<false, false><<<NG, 256, 0, stream>>>(bufO, gstart, g1, be1, ms1,
                                                  nullptr, bufX, nullptr, nullptr, nullptr);

    // ---- layer 2 ----
    k_premul<HD><<<nb_no, 256, 0, stream>>>(bufX, W2, dinv, bufH);
    k_gather<<<nb_gw, 256, 0, stream>>>(bufH, csr_src, start, deg, dinv, b2, bufO);
    k_gnorm<true, false><<<NG, 256, 0, stream>>>(bufO, gstart, g2, be2, ms2,
                                                 bufX, bufX, nullptr, nullptr, nullptr);

    // ---- layer 3 (pool + linear fused) ----
    k_premul<HD><<<nb_no, 256, 0, stream>>>(bufX, W3, dinv, bufH);
    k_gather<<<nb_gw, 256, 0, stream>>>(bufH, csr_src, start, deg, dinv, b3, bufO);
    k_gnorm<true, true><<<NG, 256, 0, stream>>>(bufO, gstart, g3, be3, ms3,
                                                bufX, bufX, Wl, bl, out);
}